// Round 14
// baseline (121.925 us; speedup 1.0000x reference)
//
#include <hip/hip_runtime.h>

#define NJ   17
#define FD   128
#define NC   128
#define NNZ  49
#define FPT  16                 // frames per tile (= MFMA M)
#define XROW (NJ*FD)            // 2176 floats per frame
#define TPB  4                  // tiles per block
#define TILEB (NJ*FPT*FD*2)     // 69632 B per LDS tile buffer (bf16)
#define WS_WT 65536             // ws offset of wt[128][64] bf16

typedef __attribute__((ext_vector_type(8))) short bf16x8;
typedef __attribute__((ext_vector_type(4))) float f32x4;

__device__ __forceinline__ ushort f2bf(float f) {   // f32 -> bf16 RNE
  unsigned u = __float_as_uint(f);
  u = (u + 0x7fffu + ((u >> 16) & 1u)) >> 16;
  return (ushort)u;
}
__device__ __forceinline__ float bf2f(ushort s) {
  return __uint_as_float(((unsigned)s) << 16);
}
__device__ __forceinline__ unsigned cvtpk(float a, float b) {
  unsigned r;
  asm("v_cvt_pk_bf16_f32 %0, %1, %2" : "=v"(r) : "v"(a), "v"(b));
  return r;
}
__device__ __forceinline__ bf16x8 pack8(float4 a, float4 b) {
  union { unsigned u[4]; bf16x8 v; } r;
  r.u[0] = cvtpk(a.x, a.y); r.u[1] = cvtpk(a.z, a.w);
  r.u[2] = cvtpk(b.x, b.y); r.u[3] = cvtpk(b.z, b.w);
  return r.v;
}
__device__ __forceinline__ void axpy(f32x4& o, float s, f32x4 h) {
  o[0] += s * h[0]; o[1] += s * h[1]; o[2] += s * h[2]; o[3] += s * h[3];
}

// LDS-only barrier: drains ds ops (lgkm), leaves vmem in flight.
#define BARR() do { asm volatile("s_waitcnt lgkmcnt(0)" ::: "memory"); \
                    __builtin_amdgcn_s_barrier(); \
                    __builtin_amdgcn_sched_barrier(0); } while (0)

// ---------------------------------------------------------------------------
// Merged compile-time skeleton table over all 17 columns (derived from the
// r6-r13-validated half tables; verified against RP row ranges).
// Per column ci: diag nnz-index dk, off-diag (out joint, nnz-k) list.
// ---------------------------------------------------------------------------
struct CIM { int dk, n, jl[4], kk[4]; };
constexpr CIM TABM[NJ] = {
  {0,  3, {1,4,7,0},   {4,12,20,0}},
  {5,  2, {0,2,0,0},   {1,7,0,0}},
  {8,  2, {1,3,0,0},   {6,10,0,0}},
  {11, 1, {2,0,0,0},   {9,0,0,0}},
  {13, 2, {0,5,0,0},   {2,15,0,0}},
  {16, 2, {4,6,0,0},   {14,18,0,0}},
  {19, 1, {5,0,0,0},   {17,0,0,0}},
  {21, 2, {0,8,0,0},   {3,23,0,0}},
  {24, 4, {7,9,11,14}, {22,28,33,41}},
  {29, 2, {8,10,0,0},  {25,31,0,0}},
  {32, 1, {9,0,0,0},   {30,0,0,0}},
  {34, 2, {8,12,0,0},  {26,36,0,0}},
  {37, 2, {11,13,0,0}, {35,39,0,0}},
  {40, 1, {12,0,0,0},  {38,0,0,0}},
  {42, 2, {8,15,0,0},  {27,44,0,0}},
  {45, 2, {14,16,0,0}, {43,47,0,0}},
  {48, 1, {15,0,0,0},  {46,0,0,0}},
};
// Early-flush: out joints whose contributor set closes at column ci.
constexpr int FLM[NJ][2] = {
  {-1,-1},{-1,-1},{1,-1},{2,3},{-1,-1},{4,-1},{5,6},{0,-1},{7,-1},
  {-1,-1},{9,10},{-1,-1},{11,-1},{12,13},{8,-1},{14,-1},{15,16}
};
constexpr int RP[NJ + 1] = {0,4,7,10,12,15,18,20,23,28,31,33,36,39,41,44,47,49};

// ---------------------------------------------------------------------------
// Prep (17 blocks x 256) — unchanged (validated r6-r13).
// ---------------------------------------------------------------------------
__global__ void prep_pack_kernel(const float* __restrict__ W,
                                 const float* __restrict__ e,
                                 bf16x8* __restrict__ Wpack,
                                 ushort* __restrict__ wt) {
  const int tid = threadIdx.x;
  if (blockIdx.x < 16) {
    const int idx = blockIdx.x * 256 + tid, n = idx >> 4, kb = idx & 15;
    const float* Wp = W + (size_t)(n >> 7) * (FD * NC) + (n & 127);
    bf16x8 v;
#pragma unroll
    for (int q = 0; q < 8; ++q) v[q] = (short)f2bf(Wp[(size_t)(kb * 8 + q) * NC]);
    Wpack[idx] = v;
  } else if (tid < NC) {
    const int c = tid;
    for (int j = 0; j < NJ; ++j) {
      const int k0 = RP[j], k1 = RP[j + 1];
      float m = -1e30f;
      for (int k = k0; k < k1; ++k) m = fmaxf(m, e[c * NNZ + k]);
      float s = 0.f;
      for (int k = k0; k < k1; ++k) s += expf(e[c * NNZ + k] - m);
      const float inv = 1.f / s;
      for (int k = k0; k < k1; ++k) wt[c * 64 + k] = f2bf(expf(e[c * NNZ + k] - m) * inv);
    }
    for (int k = NNZ; k < 64; ++k) wt[c * 64 + k] = 0;
  }
}

// ---------------------------------------------------------------------------
// Wave-specialized fused kernel. Block = 768 thr = 12 waves, 1 block/CU:
//   waves 0-7  (consumers): r7-verbatim MFMA compute for all 17 joints x
//                           128 channels; early-flush stores.
//   waves 8-11 (producers): f32 load -> cvt bf16 -> ds_write, 6-deep rolling
//                           window, loads outstanding continuously.
// Double-buffered LDS (2 x 68 KB); ONE lgkm-only barrier per tile; producers
// write buf[(i+1)&1] while consumers read buf[i&1]. vmcnt is per-wave, so
// producer load counting is never polluted by consumer stores.
// ---------------------------------------------------------------------------
__global__ __launch_bounds__(768, 3) void fused_kernel(
    const float*  __restrict__ x,
    const bf16x8* __restrict__ Wpack,
    const ushort* __restrict__ wt,
    float*        __restrict__ out) {
  __shared__ __align__(16) char xs[2 * TILEB];   // 139264 B -> 1 block/CU
  const int tid = threadIdx.x;
  const int wid = tid >> 6;
  const int t0  = blockIdx.x * TPB;

  if (wid >= 8) {
    // ======================= producers (256 lanes) =======================
    const int p = tid - 512;
    float4 a[12];   // 6-slot rolling window of float4-pairs

#define PLOAD(T, K) do {                                                    \
      const int g_ = p + (K) * 256;                                         \
      const int fr_ = g_ / (NJ * 16), rem_ = g_ - fr_ * (NJ * 16);          \
      const float* s_ = x + ((size_t)(T) * FPT + fr_) * XROW + rem_ * 8;    \
      a[((K) % 6) * 2]     = *(const float4*)s_;                            \
      a[((K) % 6) * 2 + 1] = *(const float4*)(s_ + 4);                      \
    } while (0)
#define PWRITE(BUF, K) do {                                                 \
      const int g_ = p + (K) * 256;                                         \
      const int fr_ = g_ / (NJ * 16);                                       \
      const int byte_ = (g_ * 16) ^ ((fr_ & 7) << 4);                       \
      *(bf16x8*)((BUF) + byte_) = pack8(a[((K) % 6) * 2],                   \
                                        a[((K) % 6) * 2 + 1]);              \
    } while (0)
    // 17 groups/lane (4352 total / 256 lanes, exact); window depth 6
#define PSTAGE(T, BUF) do {                                                 \
      PLOAD(T,0); PLOAD(T,1); PLOAD(T,2); PLOAD(T,3); PLOAD(T,4); PLOAD(T,5);\
      PWRITE(BUF,0);  PLOAD(T,6);  PWRITE(BUF,1);  PLOAD(T,7);              \
      PWRITE(BUF,2);  PLOAD(T,8);  PWRITE(BUF,3);  PLOAD(T,9);              \
      PWRITE(BUF,4);  PLOAD(T,10); PWRITE(BUF,5);  PLOAD(T,11);             \
      PWRITE(BUF,6);  PLOAD(T,12); PWRITE(BUF,7);  PLOAD(T,13);             \
      PWRITE(BUF,8);  PLOAD(T,14); PWRITE(BUF,9);  PLOAD(T,15);             \
      PWRITE(BUF,10); PLOAD(T,16); PWRITE(BUF,11); PWRITE(BUF,12);          \
      PWRITE(BUF,13); PWRITE(BUF,14); PWRITE(BUF,15); PWRITE(BUF,16);       \
    } while (0)

    PSTAGE(t0, xs);                       // prologue: tile 0 -> buf0
    BARR();
#pragma unroll
    for (int i = 0; i < TPB; ++i) {
      if (i + 1 < TPB) PSTAGE(t0 + i + 1, xs + ((i + 1) & 1) * TILEB);
      BARR();
    }
#undef PSTAGE
#undef PWRITE
#undef PLOAD
  } else {
    // ======================= consumers (512 lanes) =======================
    const int lane = tid & 63, l15 = lane & 15, l4 = lane >> 4;
    const int c = wid * 16 + l15;

    bf16x8 bfr[2][4];                     // persistent B frags (32 regs)
#pragma unroll
    for (int sel = 0; sel < 2; ++sel)
#pragma unroll
      for (int ks = 0; ks < 4; ++ks)
        bfr[sel][ks] = Wpack[(sel * 128 + c) * 16 + ks * 4 + l4];
    bf16x8 wtp[7];                        // softmax weights, k 0..48 (28 regs)
#pragma unroll
    for (int r = 0; r < 7; ++r)
      wtp[r] = *(const bf16x8*)(wt + c * 64 + r * 8);

    BARR();                               // buf0 staged

#pragma unroll
    for (int i = 0; i < TPB; ++i) {
      const char* cur = xs + (i & 1) * TILEB;
      float* const ob = out + (size_t)(t0 + i) * (FPT * XROW);

      f32x4 oa[NJ];
#pragma unroll
      for (int j = 0; j < NJ; ++j) oa[j] = (f32x4){0.f, 0.f, 0.f, 0.f};

#pragma unroll
      for (int ci = 0; ci < NJ; ++ci) {
        const int dk = TABM[ci].dk, nn = TABM[ci].n;
        bf16x8 af[4];
#pragma unroll
        for (int ks = 0; ks < 4; ++ks) {
          const int byte = l15 * (NJ * 256) + ci * 256 +
                           (((ks * 4 + l4) * 16) ^ ((l15 & 7) << 4));
          af[ks] = *(const bf16x8*)(cur + byte);
        }
        f32x4 h1 = (f32x4){0.f, 0.f, 0.f, 0.f};
#pragma unroll
        for (int ks = 0; ks < 4; ++ks)
          h1 = __builtin_amdgcn_mfma_f32_16x16x32_bf16(af[ks], bfr[1][ks], h1, 0, 0, 0);
        f32x4 h0 = (f32x4){0.f, 0.f, 0.f, 0.f};
#pragma unroll
        for (int ks = 0; ks < 4; ++ks)
          h0 = __builtin_amdgcn_mfma_f32_16x16x32_bf16(af[ks], bfr[0][ks], h0, 0, 0, 0);
        axpy(oa[ci], bf2f((ushort)wtp[dk >> 3][dk & 7]), h0);   // diagonal
#pragma unroll
        for (int o = 0; o < 4; ++o)
          if (o < nn)
            axpy(oa[TABM[ci].jl[o]],
                 bf2f((ushort)wtp[TABM[ci].kk[o] >> 3][TABM[ci].kk[o] & 7]), h1);

        // early flush: store + retire completed joints (acc live <= 7)
#pragma unroll
        for (int fi = 0; fi < 2; ++fi) {
          const int fj = FLM[ci][fi];
          if (fj >= 0) {
#pragma unroll
            for (int q = 0; q < 4; ++q)
              ob[(size_t)(l4 * 4 + q) * XROW + fj * FD + c] = oa[fj][q];
          }
        }
      }
      BARR();                             // done reading cur; next buf staged
    }
  }
}

// ---------------------------------------------------------------------------
extern "C" void kernel_launch(void* const* d_in, const int* in_sizes, int n_in,
                              void* d_out, int out_size, void* d_ws, size_t ws_size,
                              hipStream_t stream) {
  const float* x = (const float*)d_in[0];   // [B,T,J,F]
  const float* W = (const float*)d_in[1];   // [2,F,C]
  const float* e = (const float*)d_in[2];   // [C,NNZ]
  float* out = (float*)d_out;

  bf16x8* Wpack = (bf16x8*)d_ws;
  ushort* wt    = (ushort*)((char*)d_ws + WS_WT);

  prep_pack_kernel<<<17, 256, 0, stream>>>(W, e, Wpack, wt);

  const int frames = in_sizes[0] / XROW;    // 15552
  const int ntiles = frames / FPT;          // 972
  const int blocks = ntiles / TPB;          // 243 (exact, one per CU)
  fused_kernel<<<blocks, 768, 0, stream>>>(x, Wpack, wt, out);
}